// Round 3
// baseline (398.353 us; speedup 1.0000x reference)
//
#include <hip/hip_runtime.h>
#include <hip/hip_bf16.h>

#define S_LEN 512
#define HDIM 1024
#define H2 2048

typedef float f32x4 __attribute__((ext_vector_type(4)));
typedef float f32x2 __attribute__((ext_vector_type(2)));
typedef __bf16 bf16x8 __attribute__((ext_vector_type(8)));

// ---------------- K1: e1[b,h] = hidden[b,:] . Wa[h,0:1024] + ba[h]  (f32 exact)
// LDS-tiled: WG = 4 h-values (one per wave), lanes = b. Hidden tile staged at
// pitch 258 (even -> b64-aligned; 258%32==2 -> 2-way bank access = free).
#define E1_PITCH 258
__global__ __launch_bounds__(256) void k_e1(const float* __restrict__ hidden,
                                            const float* __restrict__ Wa,
                                            const float* __restrict__ ba,
                                            float* __restrict__ e1) {
    __shared__ float hsh[64 * E1_PITCH];
    int h = blockIdx.x * 4 + (threadIdx.x >> 6);
    int lane = threadIdx.x & 63;
    const float* wrow = Wa + (size_t)h * H2;  // hidden-half of Wa row
    float acc = 0.f;
    for (int k0 = 0; k0 < HDIM; k0 += 256) {
        __syncthreads();
        // stage hidden[0:64][k0:k0+256]
        for (int idx = threadIdx.x; idx < 4096; idx += 256) {
            int b = idx >> 6, ck = (idx & 63) << 2;
            f32x4 v = *(const f32x4*)(hidden + b * HDIM + k0 + ck);
            f32x2 lo; lo[0] = v[0]; lo[1] = v[1];
            f32x2 hi; hi[0] = v[2]; hi[1] = v[3];
            *(f32x2*)(hsh + b * E1_PITCH + ck) = lo;
            *(f32x2*)(hsh + b * E1_PITCH + ck + 2) = hi;
        }
        __syncthreads();
        const float* wr = wrow + k0;
        const float* hb = hsh + lane * E1_PITCH;
#pragma unroll 8
        for (int kk = 0; kk < 256; kk += 4) {
            f32x4 w = *(const f32x4*)(wr + kk);          // wave-uniform broadcast
            f32x2 h01 = *(const f32x2*)(hb + kk);
            f32x2 h23 = *(const f32x2*)(hb + kk + 2);
            acc += w[0] * h01[0] + w[1] * h01[1] + w[2] * h23[0] + w[3] * h23[1];
        }
    }
    e1[lane * HDIM + h] = acc + ba[h];
}

// ---------------- K2: pack Wa2 (f32) -> bf16 tiles in global_load_lds order ----
// tile (nt,kt): 128x32 bf16; chunk wi = row*4+slot holds cols (slot^swz(row))*8..
// swz(row) = (row>>1)&3.  Also zeroes the logit accumulator (d_out).
__global__ __launch_bounds__(256) void k_packB(const float* __restrict__ Wa,
                                               unsigned short* __restrict__ wsB,
                                               float* __restrict__ logits) {
    int ci = blockIdx.x * 256 + threadIdx.x;      // 16B chunk id, 0..131071
    if (ci < S_LEN * 64) logits[ci] = 0.f;        // fused k_zero (32768 floats)
    int tile = ci >> 9;
    int wi = ci & 511;
    int row = wi >> 2;
    int slot = wi & 3;
    int nt = tile >> 5, kt = tile & 31;
    int n = nt * 128 + row;
    int kk = kt * 32 + ((slot ^ ((row >> 1) & 3)) << 3);
    const float* src = Wa + (size_t)n * H2 + HDIM + kk;  // encoder half
    f32x4 a = *(const f32x4*)src;
    f32x4 b = *(const f32x4*)(src + 4);
    bf16x8 o;
    o[0] = (__bf16)a[0]; o[1] = (__bf16)a[1]; o[2] = (__bf16)a[2]; o[3] = (__bf16)a[3];
    o[4] = (__bf16)b[0]; o[5] = (__bf16)b[1]; o[6] = (__bf16)b[2]; o[7] = (__bf16)b[3];
    *(bf16x8*)(wsB + (size_t)ci * 8) = o;
}

// ---------------- K3: fused GEMM (enc->bf16 @ Wa2^T) + relu + Ws-dot -> atomics
// 128x128 tile, BK=32. A: f32 global -> reg (double-buffered) -> cvt -> swizzled
// ds_write. B: global_load_lds from packed wsB. Counted vmcnt(4) keeps next-A
// loads in flight across barrier1 (T3/T4 2-phase).
__global__ __launch_bounds__(256) void k_main(const float* __restrict__ enc,
                                              const unsigned short* __restrict__ wsB,
                                              const float* __restrict__ e1,
                                              const float* __restrict__ Ws,
                                              float* __restrict__ logits) {
    __shared__ __align__(16) unsigned short As[4096];  // [128][32] bf16, swizzled
    __shared__ __align__(16) unsigned short Bs[4096];

    int i = blockIdx.x;
    // XCD-aware mapping: the 8 n-blocks sharing an A-panel land on one XCD.
    int mt = ((i >> 6) << 3) | (i & 7);
    int nt = (i >> 3) & 7;
    int r0 = mt * 128;
    int n0 = nt * 128;

    int tid = threadIdx.x;
    int lane = tid & 63, wid = tid >> 6;
    int wr = wid >> 1, wc = wid & 1;
    int c = lane & 15, g = lane >> 4;

    // A staging addressing: thread covers rows rowA and rowA+64, 32B each.
    int rowA = tid >> 2;
    int slotA = tid & 3;
    int kkA = (slotA ^ ((rowA >> 1) & 3)) << 3;   // same for rowA+64 (swz period 8|64)
    const float* aptr0 = enc + (size_t)(r0 + rowA) * HDIM + kkA;
    const float* aptr1 = aptr0 + (size_t)64 * HDIM;

    f32x4 acc[4][4] = {};

    // prologue: A[0] into regs
    f32x4 c0 = *(const f32x4*)(aptr0);
    f32x4 c1 = *(const f32x4*)(aptr0 + 4);
    f32x4 c2 = *(const f32x4*)(aptr1);
    f32x4 c3 = *(const f32x4*)(aptr1 + 4);

    for (int kt = 0; kt < 32; ++kt) {
        // --- B stage: 2 x global_load_lds (issued FIRST; drained by vmcnt(4))
        const unsigned short* bsrc = wsB + ((size_t)(nt * 32 + kt) << 12);
        char* lb = (char*)Bs + wid * 1024;
        __builtin_amdgcn_global_load_lds(
            (const __attribute__((address_space(1))) void*)(bsrc + (size_t)tid * 8),
            (__attribute__((address_space(3))) void*)lb, 16, 0, 0);
        __builtin_amdgcn_global_load_lds(
            (const __attribute__((address_space(1))) void*)(bsrc + (size_t)(tid + 256) * 8),
            (__attribute__((address_space(3))) void*)(lb + 4096), 16, 0, 0);
        __builtin_amdgcn_sched_barrier(0);

        // --- next-iter A f32 loads (stay in flight across barrier1 + MFMA)
        int kn = (kt < 31) ? kt + 1 : 31;
        f32x4 n0v = *(const f32x4*)(aptr0 + kn * 32);
        f32x4 n1v = *(const f32x4*)(aptr0 + kn * 32 + 4);
        f32x4 n2v = *(const f32x4*)(aptr1 + kn * 32);
        f32x4 n3v = *(const f32x4*)(aptr1 + kn * 32 + 4);

        // --- convert current A, write to LDS (swizzled slots)
        bf16x8 o0, o1;
        o0[0] = (__bf16)c0[0]; o0[1] = (__bf16)c0[1]; o0[2] = (__bf16)c0[2]; o0[3] = (__bf16)c0[3];
        o0[4] = (__bf16)c1[0]; o0[5] = (__bf16)c1[1]; o0[6] = (__bf16)c1[2]; o0[7] = (__bf16)c1[3];
        o1[0] = (__bf16)c2[0]; o1[1] = (__bf16)c2[1]; o1[2] = (__bf16)c2[2]; o1[3] = (__bf16)c2[3];
        o1[4] = (__bf16)c3[0]; o1[5] = (__bf16)c3[1]; o1[6] = (__bf16)c3[2]; o1[7] = (__bf16)c3[3];
        *(bf16x8*)((char*)As + (rowA << 6) + (slotA << 4)) = o0;
        *(bf16x8*)((char*)As + ((rowA + 64) << 6) + (slotA << 4)) = o1;

        // barrier1: drain B gload_lds (oldest 2 of 6 vmem) + LDS writes; A flies on
        asm volatile("s_waitcnt vmcnt(4) lgkmcnt(0)" ::: "memory");
        __builtin_amdgcn_sched_barrier(0);
        __builtin_amdgcn_s_barrier();
        __builtin_amdgcn_sched_barrier(0);

        // --- fragments + MFMA
        bf16x8 af[4], bfr[4];
#pragma unroll
        for (int m = 0; m < 4; ++m) {
            int row = wr * 64 + m * 16 + c;
            int slot = g ^ ((row >> 1) & 3);
            af[m] = *(const bf16x8*)((const char*)As + row * 64 + slot * 16);
        }
#pragma unroll
        for (int n = 0; n < 4; ++n) {
            int rowb = wc * 64 + n * 16 + c;
            int slot = g ^ ((rowb >> 1) & 3);
            bfr[n] = *(const bf16x8*)((const char*)Bs + rowb * 64 + slot * 16);
        }
#pragma unroll
        for (int m = 0; m < 4; ++m)
#pragma unroll
            for (int n = 0; n < 4; ++n)
                acc[m][n] = __builtin_amdgcn_mfma_f32_16x16x32_bf16(af[m], bfr[n], acc[m][n], 0, 0, 0);

        // barrier2: LDS reads all retired before any wave's MFMA issue; no vmem drain
        __builtin_amdgcn_sched_barrier(0);
        __builtin_amdgcn_s_barrier();
        __builtin_amdgcn_sched_barrier(0);

        c0 = n0v; c1 = n1v; c2 = n2v; c3 = n3v;
    }

    // --- epilogue: v = relu(acc + e1[b,h]); p = v . Ws; atomicAdd into logits
    float wsv[4];
#pragma unroll
    for (int n = 0; n < 4; ++n) wsv[n] = Ws[n0 + wc * 64 + n * 16 + c];

#pragma unroll
    for (int m = 0; m < 4; ++m) {
#pragma unroll
        for (int j = 0; j < 4; ++j) {
            int rl = wr * 64 + m * 16 + g * 4 + j;
            int r = r0 + rl;
            int b = r & 63, sidx = r >> 6;
            const float* e1b = e1 + b * HDIM + n0 + wc * 64;
            float p = 0.f;
#pragma unroll
            for (int n = 0; n < 4; ++n) {
                float v = acc[m][n][j] + e1b[n * 16 + c];
                v = fmaxf(v, 0.f);
                p += v * wsv[n];
            }
            p += __shfl_xor(p, 1);
            p += __shfl_xor(p, 2);
            p += __shfl_xor(p, 4);
            p += __shfl_xor(p, 8);
            if (c == 0) atomicAdd(&logits[b * S_LEN + sidx], p);
        }
    }
}

// ---------------- K4: logits -> softmax probs, in place on d_out ----------------
__global__ __launch_bounds__(512) void k_softmax(float* __restrict__ out,
                                                 const float* __restrict__ pe,
                                                 const int* __restrict__ mask,
                                                 float scale) {
    __shared__ float red[8];
    int b = blockIdx.x, s = threadIdx.x;
    int idx = (b << 9) + s;
    float acc = out[idx];
    float logit = (mask[idx] != 0) ? -1e12f : (scale * acc + pe[idx]);
    float m = logit;
#pragma unroll
    for (int o = 32; o >= 1; o >>= 1) m = fmaxf(m, __shfl_xor(m, o));
    if ((s & 63) == 0) red[s >> 6] = m;
    __syncthreads();
    float m2 = red[0];
#pragma unroll
    for (int i2 = 1; i2 < 8; ++i2) m2 = fmaxf(m2, red[i2]);
    float e = expf(logit - m2);
    float t = e;
#pragma unroll
    for (int o = 32; o >= 1; o >>= 1) t += __shfl_xor(t, o);
    __syncthreads();
    if ((s & 63) == 0) red[s >> 6] = t;
    __syncthreads();
    float tot = 0.f;
#pragma unroll
    for (int i2 = 0; i2 < 8; ++i2) tot += red[i2];
    out[idx] = e / tot;
}

extern "C" void kernel_launch(void* const* d_in, const int* in_sizes, int n_in,
                              void* d_out, int out_size, void* d_ws, size_t ws_size,
                              hipStream_t stream) {
    const float* hidden = (const float*)d_in[0];
    const float* enc    = (const float*)d_in[1];
    const float* pe     = (const float*)d_in[2];
    const int*   mask   = (const int*)d_in[3];
    const float* Wa     = (const float*)d_in[4];
    const float* ba     = (const float*)d_in[5];
    const float* Ws     = (const float*)d_in[6];
    float* out = (float*)d_out;

    float* e1 = (float*)d_ws;                                       // 256 KB
    unsigned short* wsB = (unsigned short*)((char*)d_ws + 262144);  // 2 MB

    const float scale = 0.19494764453248462f;  // log(512)/sqrt(1024)

    k_e1<<<256, 256, 0, stream>>>(hidden, Wa, ba, e1);
    k_packB<<<512, 256, 0, stream>>>(Wa, wsB, out);
    k_main<<<2048, 256, 0, stream>>>(enc, wsB, e1, Ws, out);
    k_softmax<<<64, 512, 0, stream>>>(out, pe, mask, scale);
}

// Round 4
// 371.671 us; speedup vs baseline: 1.0718x; 1.0718x over previous
//
#include <hip/hip_runtime.h>
#include <hip/hip_bf16.h>

#define S_LEN 512
#define HDIM 1024
#define H2 2048

typedef float f32x4 __attribute__((ext_vector_type(4)));
typedef float f32x2 __attribute__((ext_vector_type(2)));
typedef __bf16 bf16x8 __attribute__((ext_vector_type(8)));

// ---------------- K1: e1[b,h] = hidden[b,:] . Wa[h,0:1024] + ba[h]  (f32 exact)
#define E1_PITCH 258
__global__ __launch_bounds__(256) void k_e1(const float* __restrict__ hidden,
                                            const float* __restrict__ Wa,
                                            const float* __restrict__ ba,
                                            float* __restrict__ e1) {
    __shared__ float hsh[64 * E1_PITCH];
    int h = blockIdx.x * 4 + (threadIdx.x >> 6);
    int lane = threadIdx.x & 63;
    const float* wrow = Wa + (size_t)h * H2;  // hidden-half of Wa row
    float acc = 0.f;
    for (int k0 = 0; k0 < HDIM; k0 += 256) {
        __syncthreads();
        for (int idx = threadIdx.x; idx < 4096; idx += 256) {
            int b = idx >> 6, ck = (idx & 63) << 2;
            f32x4 v = *(const f32x4*)(hidden + b * HDIM + k0 + ck);
            f32x2 lo; lo[0] = v[0]; lo[1] = v[1];
            f32x2 hi; hi[0] = v[2]; hi[1] = v[3];
            *(f32x2*)(hsh + b * E1_PITCH + ck) = lo;
            *(f32x2*)(hsh + b * E1_PITCH + ck + 2) = hi;
        }
        __syncthreads();
        const float* wr = wrow + k0;
        const float* hb = hsh + lane * E1_PITCH;
#pragma unroll 8
        for (int kk = 0; kk < 256; kk += 4) {
            f32x4 w = *(const f32x4*)(wr + kk);
            f32x2 h01 = *(const f32x2*)(hb + kk);
            f32x2 h23 = *(const f32x2*)(hb + kk + 2);
            acc += w[0] * h01[0] + w[1] * h01[1] + w[2] * h23[0] + w[3] * h23[1];
        }
    }
    e1[lane * HDIM + h] = acc + ba[h];
}

// ---------------- K2: pack Wa2 (f32) -> bf16 tiles (gload_lds order) + zero logits
__global__ __launch_bounds__(256) void k_packB(const float* __restrict__ Wa,
                                               unsigned short* __restrict__ wsB,
                                               float* __restrict__ logits) {
    int ci = blockIdx.x * 256 + threadIdx.x;      // 16B chunk id, 0..131071
    if (ci < S_LEN * 64) logits[ci] = 0.f;        // fused zero (32768 floats)
    int tile = ci >> 9;
    int wi = ci & 511;
    int row = wi >> 2;
    int slot = wi & 3;
    int nt = tile >> 5, kt = tile & 31;
    int n = nt * 128 + row;
    int kk = kt * 32 + ((slot ^ ((row >> 1) & 3)) << 3);
    const float* src = Wa + (size_t)n * H2 + HDIM + kk;  // encoder half
    f32x4 a = *(const f32x4*)src;
    f32x4 b = *(const f32x4*)(src + 4);
    bf16x8 o;
    o[0] = (__bf16)a[0]; o[1] = (__bf16)a[1]; o[2] = (__bf16)a[2]; o[3] = (__bf16)a[3];
    o[4] = (__bf16)b[0]; o[5] = (__bf16)b[1]; o[6] = (__bf16)b[2]; o[7] = (__bf16)b[3];
    *(bf16x8*)(wsB + (size_t)ci * 8) = o;
}

// ---------------- K3: fused GEMM (enc->bf16 @ Wa2^T) + relu + Ws-dot -> atomics
// 128x128 tile, BK=32. LDS double-buffered (write n=(t+1)&1 while MFMA reads
// c=t&1) -> ONE barrier per K-step. A: f32 -> reg (2-deep: load t+2, cvt t+1)
// -> swizzled ds_write. B: global_load_lds, drained by counted vmcnt(4) AFTER
// the MFMA phase. 32KB LDS -> 4 blocks/CU.
__global__ __launch_bounds__(256, 4) void k_main(const float* __restrict__ enc,
                                                 const unsigned short* __restrict__ wsB,
                                                 const float* __restrict__ e1,
                                                 const float* __restrict__ Ws,
                                                 float* __restrict__ logits) {
    __shared__ __align__(16) unsigned short As[8192];  // 2 x [128][32] bf16, swizzled
    __shared__ __align__(16) unsigned short Bs[8192];

    int i = blockIdx.x;
    // XCD-aware: the 8 n-blocks sharing an A-panel land on one XCD.
    int mt = ((i >> 6) << 3) | (i & 7);
    int nt = (i >> 3) & 7;
    int r0 = mt * 128;
    int n0 = nt * 128;

    int tid = threadIdx.x;
    int lane = tid & 63, wid = tid >> 6;
    int wr = wid >> 1, wc = wid & 1;
    int c = lane & 15, g = lane >> 4;

    // A staging: thread covers rows rowA and rowA+64, 32B (8 floats) each.
    int rowA = tid >> 2;
    int slotA = tid & 3;
    int kkA = (slotA ^ ((rowA >> 1) & 3)) << 3;
    const float* aptr0 = enc + (size_t)(r0 + rowA) * HDIM + kkA;
    const float* aptr1 = aptr0 + (size_t)64 * HDIM;
    int awo0 = (rowA << 6) + (slotA << 4);          // byte offset in an A buffer
    int awo1 = ((rowA + 64) << 6) + (slotA << 4);

    f32x4 acc[4][4] = {};

    // ---- prologue: fill buf0 (A(0),B(0)); A(1) -> regs
    {
        const unsigned short* bsrc = wsB + ((size_t)(nt * 32) << 12);
        char* lb = (char*)Bs + wid * 1024;
        __builtin_amdgcn_global_load_lds(
            (const __attribute__((address_space(1))) void*)(bsrc + (size_t)tid * 8),
            (__attribute__((address_space(3))) void*)lb, 16, 0, 0);
        __builtin_amdgcn_global_load_lds(
            (const __attribute__((address_space(1))) void*)(bsrc + (size_t)(tid + 256) * 8),
            (__attribute__((address_space(3))) void*)(lb + 4096), 16, 0, 0);
    }
    __builtin_amdgcn_sched_barrier(0);
    f32x4 t0 = *(const f32x4*)(aptr0);
    f32x4 t1 = *(const f32x4*)(aptr0 + 4);
    f32x4 t2 = *(const f32x4*)(aptr1);
    f32x4 t3 = *(const f32x4*)(aptr1 + 4);
    f32x4 p0 = *(const f32x4*)(aptr0 + 32);
    f32x4 p1 = *(const f32x4*)(aptr0 + 36);
    f32x4 p2 = *(const f32x4*)(aptr1 + 32);
    f32x4 p3 = *(const f32x4*)(aptr1 + 36);
    {
        bf16x8 o0, o1;
        o0[0] = (__bf16)t0[0]; o0[1] = (__bf16)t0[1]; o0[2] = (__bf16)t0[2]; o0[3] = (__bf16)t0[3];
        o0[4] = (__bf16)t1[0]; o0[5] = (__bf16)t1[1]; o0[6] = (__bf16)t1[2]; o0[7] = (__bf16)t1[3];
        o1[0] = (__bf16)t2[0]; o1[1] = (__bf16)t2[1]; o1[2] = (__bf16)t2[2]; o1[3] = (__bf16)t2[3];
        o1[4] = (__bf16)t3[0]; o1[5] = (__bf16)t3[1]; o1[6] = (__bf16)t3[2]; o1[7] = (__bf16)t3[3];
        *(bf16x8*)((char*)As + awo0) = o0;
        *(bf16x8*)((char*)As + awo1) = o1;
    }
    asm volatile("s_waitcnt vmcnt(4) lgkmcnt(0)" ::: "memory");
    __builtin_amdgcn_sched_barrier(0);
    __builtin_amdgcn_s_barrier();
    __builtin_amdgcn_sched_barrier(0);

#pragma unroll 2
    for (int t = 0; t < 32; ++t) {
        int cb = (t & 1) << 13;        // current buf byte offset
        int nb = cb ^ 8192;            // next buf

        if (t < 31) {
            // B(t+1) -> Bs[next] (issued FIRST; counted drain after MFMA)
            const unsigned short* bsrc = wsB + ((size_t)(nt * 32 + t + 1) << 12);
            char* lbw = (char*)Bs + nb + wid * 1024;
            __builtin_amdgcn_global_load_lds(
                (const __attribute__((address_space(1))) void*)(bsrc + (size_t)tid * 8),
                (__attribute__((address_space(3))) void*)lbw, 16, 0, 0);
            __builtin_amdgcn_global_load_lds(
                (const __attribute__((address_space(1))) void*)(bsrc + (size_t)(tid + 256) * 8),
                (__attribute__((address_space(3))) void*)(lbw + 4096), 16, 0, 0);
            __builtin_amdgcn_sched_barrier(0);

            // A(t+2) f32 loads (in flight across this iter's MFMA + barrier)
            int kn = (t + 2 < 32) ? t + 2 : 31;
            f32x4 q0 = *(const f32x4*)(aptr0 + kn * 32);
            f32x4 q1 = *(const f32x4*)(aptr0 + kn * 32 + 4);
            f32x4 q2 = *(const f32x4*)(aptr1 + kn * 32);
            f32x4 q3 = *(const f32x4*)(aptr1 + kn * 32 + 4);

            // cvt A(t+1) (loaded a full iteration ago) -> As[next]
            bf16x8 o0, o1;
            o0[0] = (__bf16)p0[0]; o0[1] = (__bf16)p0[1]; o0[2] = (__bf16)p0[2]; o0[3] = (__bf16)p0[3];
            o0[4] = (__bf16)p1[0]; o0[5] = (__bf16)p1[1]; o0[6] = (__bf16)p1[2]; o0[7] = (__bf16)p1[3];
            o1[0] = (__bf16)p2[0]; o1[1] = (__bf16)p2[1]; o1[2] = (__bf16)p2[2]; o1[3] = (__bf16)p2[3];
            o1[4] = (__bf16)p3[0]; o1[5] = (__bf16)p3[1]; o1[6] = (__bf16)p3[2]; o1[7] = (__bf16)p3[3];
            *(bf16x8*)((char*)As + nb + awo0) = o0;
            *(bf16x8*)((char*)As + nb + awo1) = o1;
            p0 = q0; p1 = q1; p2 = q2; p3 = q3;
        }

        // ---- MFMA phase on buf c
        bf16x8 af[4], bfr[4];
#pragma unroll
        for (int m = 0; m < 4; ++m) {
            int row = wr * 64 + m * 16 + c;
            int slot = g ^ ((row >> 1) & 3);
            af[m] = *(const bf16x8*)((const char*)As + cb + row * 64 + slot * 16);
        }
#pragma unroll
        for (int n = 0; n < 4; ++n) {
            int rowb = wc * 64 + n * 16 + c;
            int slot = g ^ ((rowb >> 1) & 3);
            bfr[n] = *(const bf16x8*)((const char*)Bs + cb + rowb * 64 + slot * 16);
        }
#pragma unroll
        for (int m = 0; m < 4; ++m)
#pragma unroll
            for (int n = 0; n < 4; ++n)
                acc[m][n] = __builtin_amdgcn_mfma_f32_16x16x32_bf16(af[m], bfr[n], acc[m][n], 0, 0, 0);

        if (t < 31) {
            // drain B(t+1) gload_lds (A(t+2) stays in flight) + staging ds_writes
            asm volatile("s_waitcnt vmcnt(4) lgkmcnt(0)" ::: "memory");
            __builtin_amdgcn_sched_barrier(0);
            __builtin_amdgcn_s_barrier();
            __builtin_amdgcn_sched_barrier(0);
        }
    }

    // --- epilogue: v = relu(acc + e1[b,h]); p = v . Ws; atomicAdd into logits
    float wsv[4];
#pragma unroll
    for (int n = 0; n < 4; ++n) wsv[n] = Ws[n0 + wc * 64 + n * 16 + c];

#pragma unroll
    for (int m = 0; m < 4; ++m) {
#pragma unroll
        for (int j = 0; j < 4; ++j) {
            int rl = wr * 64 + m * 16 + g * 4 + j;
            int r = r0 + rl;
            int b = r & 63, sidx = r >> 6;
            const float* e1b = e1 + b * HDIM + n0 + wc * 64;
            float p = 0.f;
#pragma unroll
            for (int n = 0; n < 4; ++n) {
                float v = acc[m][n][j] + e1b[n * 16 + c];
                v = fmaxf(v, 0.f);
                p += v * wsv[n];
            }
            p += __shfl_xor(p, 1);
            p += __shfl_xor(p, 2);
            p += __shfl_xor(p, 4);
            p += __shfl_xor(p, 8);
            if (c == 0) atomicAdd(&logits[b * S_LEN + sidx], p);
        }
    }
}

// ---------------- K4: logits -> softmax probs, in place on d_out ----------------
__global__ __launch_bounds__(512) void k_softmax(float* __restrict__ out,
                                                 const float* __restrict__ pe,
                                                 const int* __restrict__ mask,
                                                 float scale) {
    __shared__ float red[8];
    int b = blockIdx.x, s = threadIdx.x;
    int idx = (b << 9) + s;
    float acc = out[idx];
    float logit = (mask[idx] != 0) ? -1e12f : (scale * acc + pe[idx]);
    float m = logit;
#pragma unroll
    for (int o = 32; o >= 1; o >>= 1) m = fmaxf(m, __shfl_xor(m, o));
    if ((s & 63) == 0) red[s >> 6] = m;
    __syncthreads();
    float m2 = red[0];
#pragma unroll
    for (int i2 = 1; i2 < 8; ++i2) m2 = fmaxf(m2, red[i2]);
    float e = expf(logit - m2);
    float t = e;
#pragma unroll
    for (int o = 32; o >= 1; o >>= 1) t += __shfl_xor(t, o);
    __syncthreads();
    if ((s & 63) == 0) red[s >> 6] = t;
    __syncthreads();
    float tot = 0.f;
#pragma unroll
    for (int i2 = 0; i2 < 8; ++i2) tot += red[i2];
    out[idx] = e / tot;
}

extern "C" void kernel_launch(void* const* d_in, const int* in_sizes, int n_in,
                              void* d_out, int out_size, void* d_ws, size_t ws_size,
                              hipStream_t stream) {
    const float* hidden = (const float*)d_in[0];
    const float* enc    = (const float*)d_in[1];
    const float* pe     = (const float*)d_in[2];
    const int*   mask   = (const int*)d_in[3];
    const float* Wa     = (const float*)d_in[4];
    const float* ba     = (const float*)d_in[5];
    const float* Ws     = (const float*)d_in[6];
    float* out = (float*)d_out;

    float* e1 = (float*)d_ws;                                       // 256 KB
    unsigned short* wsB = (unsigned short*)((char*)d_ws + 262144);  // 2 MB

    const float scale = 0.19494764453248462f;  // log(512)/sqrt(1024)

    k_e1<<<256, 256, 0, stream>>>(hidden, Wa, ba, e1);
    k_packB<<<512, 256, 0, stream>>>(Wa, wsB, out);
    k_main<<<2048, 256, 0, stream>>>(enc, wsB, e1, Ws, out);
    k_softmax<<<64, 512, 0, stream>>>(out, pe, mask, scale);
}